// Round 11
// baseline (17007.845 us; speedup 1.0000x reference)
//
#include <hip/hip_runtime.h>
#include <hip/hip_bf16.h>
#include <math.h>

#define GBK 256          // grid blocks (1 per CU, co-resident)
#define NT  512          // threads per block (8 waves)

constexpr int T_STEPS = 600;
constexpr int TXT     = 200;
constexpr int NMEL    = 80;
constexpr int H       = 1024;
constexpr int ATT     = 640;
constexpr int DIN     = H + ATT;   // 1664
constexpr int GATE_B  = 200;       // gate-output block (no SC work)

// ---- ws layout: bf16 region (ushort element offsets) ----
constexpr size_t O_WQ    = 0;                                  // 640*1024
constexpr size_t O_WIHA  = O_WQ   + (size_t)ATT*H;             // 4096*80
constexpr size_t O_WIH0  = O_WIHA + (size_t)4*H*NMEL;          // 4096*1664
constexpr size_t O_WHH1  = O_WIH0 + (size_t)4*H*DIN;           // 4096*1024
constexpr size_t O_WD1   = O_WHH1 + (size_t)4*H*H;             // 1024*1024
constexpr size_t O_WD2   = O_WD1  + (size_t)H*H;
constexpr size_t O_KEYS  = O_WD2  + (size_t)H*H;               // 200*640 row-major
constexpr size_t O_VALS  = O_KEYS + (size_t)TXT*ATT;           // 200*640 row-major
constexpr size_t O_END_U = O_VALS + (size_t)TXT*ATT;
constexpr size_t RBYTE   = ((O_END_U*2 + 255)/256)*256;        // record region
// records: 8 phases x 256 blocks x 32B. rec(p,b) = R + (p*256+b)*8 (uint units)
// layout: [f0|ep|f1|ep][f2|ep|f3|ep]  (8B-atomic data+epoch pairs, RCCL-LL style)
constexpr int RECN = 8*GBK*8;   // uints to zero

typedef unsigned short ushortT;
typedef ushortT us4 __attribute__((ext_vector_type(4)));
typedef ushortT us8 __attribute__((ext_vector_type(8)));
typedef unsigned uv4 __attribute__((ext_vector_type(4)));   // native vec for asm
typedef float    fv4 __attribute__((ext_vector_type(4)));

__device__ __forceinline__ float bf2f(ushortT u) {
  return __uint_as_float(((unsigned)u) << 16);
}
__device__ __forceinline__ ushortT f2bf(float x) {
  __hip_bfloat16 h = __float2bfloat16(x);
  ushortT u; __builtin_memcpy(&u, &h, 2); return u;
}
__device__ __forceinline__ us4 cvt4(float4 a) {
  return us4{ f2bf(a.x), f2bf(a.y), f2bf(a.z), f2bf(a.w) };
}
__device__ __forceinline__ float sigf(float x) { return 1.0f / (1.0f + expf(-x)); }
__device__ __forceinline__ float tanhfast(float x) {
  float e = __expf(2.0f * x);
  return (e - 1.0f) / (e + 1.0f);
}

__device__ __forceinline__ float red64(float v) {
  #pragma unroll
  for (int off = 32; off > 0; off >>= 1) v += __shfl_xor(v, off, 64);
  return v;
}

// ---- payload-record publish / wait (single LLC round-trip sync+data) ----
__device__ __forceinline__ void rpub4(unsigned* rec, float a, float b, float c,
                                      float d, unsigned e) {
  uv4 lo, hi;
  lo.x = __float_as_uint(a); lo.y = e; lo.z = __float_as_uint(b); lo.w = e;
  hi.x = __float_as_uint(c); hi.y = e; hi.z = __float_as_uint(d); hi.w = e;
  asm volatile("global_store_dwordx4 %0, %2, off sc0 sc1\n\t"
               "global_store_dwordx4 %1, %3, off sc0 sc1"
               :: "v"(rec), "v"(rec + 4), "v"(lo), "v"(hi) : "memory");
}
__device__ __forceinline__ float4 rwait4(const unsigned* rec, unsigned e) {
  uv4 lo, hi;
  const unsigned* r2 = rec + 4;
  while (true) {
    asm volatile("global_load_dwordx4 %0, %2, off sc0 sc1\n\t"
                 "global_load_dwordx4 %1, %3, off sc0 sc1\n\t"
                 "s_waitcnt vmcnt(0)"
                 : "=&v"(lo), "=&v"(hi) : "v"(rec), "v"(r2) : "memory");
    if (lo.y >= e && lo.w >= e && hi.y >= e && hi.w >= e) break;
    __builtin_amdgcn_s_sleep(1);
  }
  float4 o;
  o.x = __uint_as_float(lo.x); o.y = __uint_as_float(lo.z);
  o.z = __uint_as_float(hi.x); o.w = __uint_as_float(hi.z);
  return o;
}

// ---- conflict-free dots: lane handles float4/us4 index c*64+lane ----
__device__ __forceinline__ float dotbf(const ushortT* __restrict__ Wrow,
                                       const float* __restrict__ v, int lane) {
  const us4* w4 = (const us4*)Wrow;
  const float4* v4 = (const float4*)v;
  float s = 0.f;
  #pragma unroll
  for (int c = 0; c < 4; ++c) {
    us4 w = w4[c*64 + lane];
    float4 x = v4[c*64 + lane];
    s += bf2f(w[0])*x.x + bf2f(w[1])*x.y + bf2f(w[2])*x.z + bf2f(w[3])*x.w;
  }
  return s;
}
__device__ __forceinline__ float dotf(const float* __restrict__ Wrow,
                                      const float* __restrict__ v, int lane) {
  const float4* w4 = (const float4*)Wrow;
  const float4* v4 = (const float4*)v;
  float s = 0.f;
  #pragma unroll
  for (int c = 0; c < 4; ++c) {
    float4 w = w4[c*64 + lane], x = v4[c*64 + lane];
    s += w.x*x.x + w.y*x.y + w.z*x.z + w.w*x.w;
  }
  return s;
}
__device__ __forceinline__ float dot200(const float* __restrict__ a,
                                        const float* __restrict__ e, int lane) {
  float s = a[lane]*e[lane] + a[64+lane]*e[64+lane] + a[128+lane]*e[128+lane];
  if (lane < 8) s += a[192+lane]*e[192+lane];
  return s;
}

// ---------- prep kernels ----------
__global__ void conv_bf16(const float* __restrict__ src, ushortT* __restrict__ dst, size_t n) {
  size_t i  = blockIdx.x * (size_t)blockDim.x + threadIdx.x;
  size_t st = (size_t)gridDim.x * blockDim.x;
  for (; i < n; i += st) dst[i] = f2bf(src[i]);
}

__global__ void prep_kv(const float* __restrict__ text, const float* __restrict__ Wk,
                        const float* __restrict__ Wv, ushortT* __restrict__ keys,
                        ushortT* __restrict__ vals) {
  __shared__ float tx[ATT];
  const int t = blockIdx.x;
  for (int i = threadIdx.x; i < ATT; i += blockDim.x) tx[i] = text[(size_t)t*ATT + i];
  __syncthreads();
  for (int a = threadIdx.x; a < 2*ATT; a += blockDim.x) {
    const int which = (a >= ATT);
    const int ar = a - which*ATT;
    const float4* w4 = (const float4*)((which ? Wv : Wk) + (size_t)ar*ATT);
    const float4* t4 = (const float4*)tx;
    float s = 0.f;
    for (int i = 0; i < ATT/4; ++i) {
      float4 w = w4[i], x = t4[i];
      s += w.x*x.x + w.y*x.y + w.z*x.z + w.w*x.w;
    }
    (which ? vals : keys)[(size_t)t*ATT + ar] = f2bf(s);
  }
}

__global__ void prep_zero(unsigned* R) {
  int i = blockIdx.x * blockDim.x + threadIdx.x;
  if (i < RECN) R[i] = 0u;
}

// ---------- persistent AR kernel ----------
__global__ void __launch_bounds__(NT, 1)
ar_persist(const float* __restrict__ residual,
           const float* __restrict__ Whh_a, const float* __restrict__ Whh0g,
           const float* __restrict__ Wih1g,
           const float* __restrict__ b_a, const float* __restrict__ v_attn,
           const float* __restrict__ b0, const float* __restrict__ b1,
           const float* __restrict__ bd1, const float* __restrict__ bd2,
           const float* __restrict__ Wc, const float* __restrict__ bc,
           const float* __restrict__ Wg, const float* __restrict__ bg,
           float* __restrict__ out, void* __restrict__ wsraw)
{
  const int tid  = threadIdx.x;
  const int bid  = blockIdx.x;
  const int wid  = tid >> 6;     // 8 waves
  const int lane = tid & 63;

  const ushortT* uws = (const ushortT*)wsraw;
  unsigned* R = (unsigned*)((char*)wsraw + RBYTE);
  #define Rp(p, b) (R + (((p)*GBK + (b)) * 8))

  const ushortT* wq    = uws + O_WQ;
  const ushortT* wiha  = uws + O_WIHA;
  const ushortT* wih0s = uws + O_WIH0;
  const ushortT* whh1s = uws + O_WHH1;
  const ushortT* wd1   = uws + O_WD1;
  const ushortT* wd2   = uws + O_WD2;
  const ushortT* keys  = uws + O_KEYS;
  const ushortT* vals  = uws + O_VALS;

  // block owns units [bid*4, bid*4+4); 16 z-rows; wave wid -> rl 2w, 2w+1
  const int ub = bid*4;
  const int rlA = wid*2, rlB = wid*2 + 1;
  const int zrA = (rlA>>2)*H + ub + (rlA&3);
  const int zrB = (rlB>>2)*H + ub + (rlB&3);

  __shared__ __align__(16) ushortT lWhha[16*H];   // 32 KB
  __shared__ __align__(16) ushortT lWhh0[16*H];   // 32 KB
  __shared__ __align__(16) ushortT lWih1[16*H];   // 32 KB
  __shared__ __align__(16) ushortT lWd1[4*H];     // 8 KB
  __shared__ __align__(16) ushortT lWd2[4*H];     // 8 KB
  __shared__ __align__(16) ushortT lWq[3*H];      // 6 KB
  __shared__ __align__(16) float   V0[16*TXT];    // 12.8 KB
  __shared__ __align__(16) float   vg[TXT];
  __shared__ __align__(16) float   lvatt[ATT];
  __shared__ __align__(16) float   lha[H], lh0[H], lh1[H];
  __shared__ __align__(16) float   shq[ATT];
  __shared__ __align__(16) float   shv[H];
  __shared__ __align__(16) float   shx[128];
  __shared__ __align__(16) float   sce[TXT + 64];
  __shared__ float zl[16], zp[16], zaH[16], z0H[16], z1H[16];
  __shared__ float cA[4], c0S[4], c1S[4], misc2[4];

  // ---- init: stage LDS weights ----
  {
    us4* dA = (us4*)lWhha; us4* dC = (us4*)lWhh0; us4* dD = (us4*)lWih1;
    #pragma unroll
    for (int j = 0; j < 2; ++j) {
      const int rl = wid*2 + j;
      const int zr = (rl>>2)*H + ub + (rl&3);
      #pragma unroll
      for (int c = 0; c < 4; ++c) {
        const int ei = c*64 + lane;
        dA[rl*256 + ei] = cvt4(*(const float4*)(Whh_a + (size_t)zr*H + ei*4));
        dC[rl*256 + ei] = cvt4(*(const float4*)(Whh0g + (size_t)zr*H + ei*4));
        dD[rl*256 + ei] = cvt4(*(const float4*)(Wih1g + (size_t)zr*H + ei*4));
      }
    }
    if (wid < 4) {
      const us4* s1 = (const us4*)(wd1 + (size_t)(bid*4 + wid)*H);
      #pragma unroll
      for (int c = 0; c < 4; ++c)
        ((us4*)lWd1)[wid*256 + c*64 + lane] = s1[c*64 + lane];
    } else {
      const int w = wid - 4;
      const us4* s2 = (const us4*)(wd2 + (size_t)(bid*4 + w)*H);
      #pragma unroll
      for (int c = 0; c < 4; ++c)
        ((us4*)lWd2)[w*256 + c*64 + lane] = s2[c*64 + lane];
    }
    for (int w = 0; w < 3; ++w) {
      const int qr = bid + w*GBK;
      if (qr < ATT) {
        const us4* sq = (const us4*)(wq + (size_t)qr*H);
        for (int i = tid; i < 256; i += NT) ((us4*)lWq)[w*256 + i] = sq[i];
      }
    }
    for (int i = tid; i < ATT; i += NT) lvatt[i] = v_attn[i];
  }
  // ---- init: V0[r][t] = Wih0_row[H:] . v_t ; vg (gate block) ----
  for (int idx = tid; idx < 16*TXT; idx += NT) {
    const int r = idx / TXT, t = idx - r*TXT;
    const int zr = (r>>2)*H + ub + (r&3);
    const us8* wp = (const us8*)(wih0s + (size_t)zr*DIN + H);
    const us8* vp = (const us8*)(vals + (size_t)t*ATT);
    float acc = 0.f;
    for (int c = 0; c < ATT/8; ++c) {
      us8 w = wp[c], v = vp[c];
      #pragma unroll
      for (int e = 0; e < 8; ++e) acc += bf2f(w[e]) * bf2f(v[e]);
    }
    V0[r*TXT + t] = acc;
  }
  if (bid == GATE_B) {
    for (int t = tid; t < TXT; t += NT) {
      const float4* wp = (const float4*)(Wg + H);
      const us4* vp = (const us4*)(vals + (size_t)t*ATT);
      float acc = 0.f;
      for (int c = 0; c < ATT/4; ++c) {
        float4 w = wp[c]; us4 v = vp[c];
        acc += w.x*bf2f(v[0]) + w.y*bf2f(v[1]) + w.z*bf2f(v[2]) + w.w*bf2f(v[3]);
      }
      vg[t] = acc;
    }
  }
  if (tid < 16) { zaH[tid] = 0.f; z0H[tid] = 0.f; z1H[tid] = 0.f; }
  if (tid < 4)  { cA[tid] = 0.f; c0S[tid] = 0.f; c1S[tid] = 0.f; }
  __syncthreads();

  for (int s = 0; s < T_STEPS; ++s) {
    const unsigned e = (unsigned)s + 1u;

    // ===== P1: consume x (phase0, epoch>=s) ; ha ; publish phase1 =====
    if (tid < NMEL) {
      float4 r = rwait4(Rp(0, tid), (unsigned)s);
      shx[tid] = r.x;
    }
    __syncthreads();
    {
      float sA = 0.f, sB = 0.f;
      if (lane < 20) {
        float4 xv = ((const float4*)shx)[lane];
        us4 w = ((const us4*)wiha)[(size_t)zrA*20 + lane];
        sA = bf2f(w[0])*xv.x + bf2f(w[1])*xv.y + bf2f(w[2])*xv.z + bf2f(w[3])*xv.w;
        w = ((const us4*)wiha)[(size_t)zrB*20 + lane];
        sB = bf2f(w[0])*xv.x + bf2f(w[1])*xv.y + bf2f(w[2])*xv.z + bf2f(w[3])*xv.w;
      }
      sA = red64(sA) + zaH[rlA] + b_a[zrA];
      sB = red64(sB) + zaH[rlB] + b_a[zrB];
      if (lane == 0) { zl[rlA] = sA; zl[rlB] = sB; }
    }
    __syncthreads();
    if (tid == 0) {
      float h[4];
      #pragma unroll
      for (int u = 0; u < 4; ++u) {
        float c = sigf(zl[4+u])*cA[u] + sigf(zl[u])*tanhf(zl[8+u]);
        cA[u] = c;
        h[u] = sigf(zl[12+u])*tanhf(c);
      }
      rpub4(Rp(1, bid), h[0], h[1], h[2], h[3], e);
    }

    // ===== P2: consume ha ; q (wave0, publish) ; zp ; SC score (wave0) =====
    if (tid < GBK) {
      float4 r = rwait4(Rp(1, tid), e);
      ((float4*)lha)[tid] = r;
    }
    __syncthreads();
    if (wid == 0) {
      float q0 = red64(dotbf(lWq, lha, lane));
      float q1 = red64(dotbf(lWq + H, lha, lane));
      float q2 = 0.f;
      if (bid < ATT - 2*GBK) q2 = red64(dotbf(lWq + 2*H, lha, lane));
      if (lane == 0) rpub4(Rp(2, bid), q0, q1, q2, 0.f, e);
    }
    if (bid == GATE_B && wid == 3) {
      float sg = red64(dotf(Wg, lha, lane));
      if (lane == 0) misc2[0] = sg;
    }
    {
      const bool earlyzp = (wid >= 4) || (bid >= TXT);
      if (earlyzp) {
        float sA = red64(dotbf(wih0s + (size_t)zrA*DIN, lha, lane)) + z0H[rlA] + b0[zrA];
        float sB = red64(dotbf(wih0s + (size_t)zrB*DIN, lha, lane)) + z0H[rlB] + b0[zrB];
        if (lane == 0) { zp[rlA] = sA; zp[rlB] = sB; }
      }
      if (bid < TXT) {
        if (tid < GBK) {
          float4 r = rwait4(Rp(2, tid), e);
          shq[tid] = r.x; shq[256 + tid] = r.y;
          if (tid < 128) shq[512 + tid] = r.z;
        }
        __syncthreads();
        if (wid == 0) {
          const us4* kp = (const us4*)(keys + (size_t)bid*ATT);
          float ss = 0.f;
          for (int c = lane; c < 160; c += 64) {
            us4 k = kp[c];
            float4 q4 = ((const float4*)shq)[c];
            float4 v4 = ((const float4*)lvatt)[c];
            ss += tanhfast(bf2f(k[0]) + q4.x)*v4.x + tanhfast(bf2f(k[1]) + q4.y)*v4.y
                + tanhfast(bf2f(k[2]) + q4.z)*v4.z + tanhfast(bf2f(k[3]) + q4.w)*v4.w;
          }
          ss = red64(ss);
          if (lane == 0) rpub4(Rp(3, bid), ss, 0.f, 0.f, 0.f, e);
        }
      }
      if (!earlyzp) {
        float sA = red64(dotbf(wih0s + (size_t)zrA*DIN, lha, lane)) + z0H[rlA] + b0[zrA];
        float sB = red64(dotbf(wih0s + (size_t)zrB*DIN, lha, lane)) + z0H[rlB] + b0[zrB];
        if (lane == 0) { zp[rlA] = sA; zp[rlB] = sB; }
      }
    }

    // ===== P3: consume scores ; softmax-weights ; h0 publish ; gate out =====
    if (tid < TXT) {
      float4 r = rwait4(Rp(3, tid), e);
      sce[tid] = __expf(r.x);         // |score| <= sum|v_attn| ~ 10: safe
    }
    __syncthreads();
    if (wid == 0) {
      float pz = sce[lane] + sce[64+lane] + sce[128+lane]
               + (lane < 8 ? sce[192+lane] : 0.f);
      pz = red64(pz);
      if (lane == 0) misc2[1] = 1.0f / pz;
    }
    {
      float rA = red64(dot200(V0 + rlA*TXT, sce, lane));
      float rB = red64(dot200(V0 + rlB*TXT, sce, lane));
      if (lane == 0) { zl[rlA] = rA; zl[rlB] = rB; }
    }
    __syncthreads();
    if (tid == 0) {
      const float invZ = misc2[1];
      float h[4];
      #pragma unroll
      for (int u = 0; u < 4; ++u) {
        float iv = zl[u]*invZ   + zp[u];
        float fv = zl[4+u]*invZ + zp[4+u];
        float gv = zl[8+u]*invZ + zp[8+u];
        float ov = zl[12+u]*invZ + zp[12+u];
        float c = sigf(fv)*c0S[u] + sigf(iv)*tanhf(gv);
        c0S[u] = c;
        h[u] = sigf(ov)*tanhf(c);
      }
      rpub4(Rp(4, bid), h[0], h[1], h[2], h[3], e);
    }
    if (bid == GATE_B && wid == 3) {
      float sg = red64(dot200(vg, sce, lane)) * misc2[1];
      if (lane == 0) out[T_STEPS*NMEL + s] = sigf(sg + misc2[0] + bg[0]);
    }

    // ===== P4: consume h0 ; z1 -> h1 publish ; shadow z0H =====
    if (tid < GBK) {
      float4 r = rwait4(Rp(4, tid), e);
      ((float4*)lh0)[tid] = r;
    }
    __syncthreads();
    {
      float sA = red64(dotbf(lWih1 + rlA*H, lh0, lane)) + z1H[rlA] + b1[zrA];
      float sB = red64(dotbf(lWih1 + rlB*H, lh0, lane)) + z1H[rlB] + b1[zrB];
      if (lane == 0) { zl[rlA] = sA; zl[rlB] = sB; }
    }
    __syncthreads();
    if (tid == 0) {
      float h[4];
      #pragma unroll
      for (int u = 0; u < 4; ++u) {
        float c = sigf(zl[4+u])*c1S[u] + sigf(zl[u])*tanhf(zl[8+u]);
        c1S[u] = c;
        h[u] = sigf(zl[12+u])*tanhf(c);
      }
      rpub4(Rp(5, bid), h[0], h[1], h[2], h[3], e);
    }
    {
      float pA = red64(dotbf(lWhh0 + rlA*H, lh0, lane));
      float pB = red64(dotbf(lWhh0 + rlB*H, lh0, lane));
      if (lane == 0) { z0H[rlA] = pA; z0H[rlB] = pB; }
    }

    // ===== P5: consume h1 ; d1 rows (wave0, publish) ; shadow zaH =====
    if (tid < GBK) {
      float4 r = rwait4(Rp(5, tid), e);
      ((float4*)lh1)[tid] = r;
    }
    __syncthreads();
    if (wid == 0) {
      float dv[4];
      #pragma unroll
      for (int u = 0; u < 4; ++u) {
        float t6 = red64(dotbf(lWd1 + u*H, lh1, lane)) + bd1[bid*4 + u];
        dv[u] = tanhf(t6);
      }
      if (lane == 0) rpub4(Rp(6, bid), dv[0], dv[1], dv[2], dv[3], e);
    }
    {
      float pA = red64(dotbf(lWhha + rlA*H, lha, lane));
      float pB = red64(dotbf(lWhha + rlB*H, lha, lane));
      if (lane == 0) { zaH[rlA] = pA; zaH[rlB] = pB; }
    }

    // ===== P6: consume d1 ; d rows (wave0, publish) ; shadow z1H =====
    if (tid < GBK) {
      float4 r = rwait4(Rp(6, tid), e);
      ((float4*)shv)[tid] = r;
    }
    __syncthreads();
    if (wid == 0) {
      float dv[4];
      #pragma unroll
      for (int u = 0; u < 4; ++u) {
        float t7 = red64(dotbf(lWd2 + u*H, shv, lane)) + bd2[bid*4 + u];
        dv[u] = tanhf(t7);
      }
      if (lane == 0) rpub4(Rp(7, bid), dv[0], dv[1], dv[2], dv[3], e);
    }
    {
      float pA = red64(dotbf(whh1s + (size_t)zrA*H, lh1, lane));
      float pB = red64(dotbf(whh1s + (size_t)zrB*H, lh1, lane));
      if (lane == 0) { z1H[rlA] = pA; z1H[rlB] = pB; }
    }

    // ===== P7 (blocks<80): consume d ; dec_out ; out ; publish x =====
    if (bid < NMEL) {
      __syncthreads();                 // protect shv (wave0 read in P6) from re-write
      if (tid < GBK) {
        float4 r = rwait4(Rp(7, tid), e);
        ((float4*)shv)[tid] = r;
      }
      __syncthreads();
      if (wid == 0) {
        float sl = red64(dotf(Wc + (size_t)bid*H, shv, lane)) + bc[bid];
        float sb = red64(dotf(Wc + (size_t)(NMEL + bid)*H, shv, lane)) + bc[NMEL + bid];
        if (lane == 0) {
          const int idx = T_STEPS - 1 - s;
          const float r = residual[idx*NMEL + bid];
          const float o = (r - sb) * expf(-sl);
          out[idx*NMEL + bid] = o;
          rpub4(Rp(0, bid), o, 0.f, 0.f, 0.f, e);
        }
      }
    }
  }
  #undef Rp
}

extern "C" void kernel_launch(void* const* d_in, const int* in_sizes, int n_in,
                              void* d_out, int out_size, void* d_ws, size_t ws_size,
                              hipStream_t stream) {
  const float* residual = (const float*)d_in[0];
  const float* text   = (const float*)d_in[1];
  const float* Wih_a  = (const float*)d_in[2];
  const float* Whh_a  = (const float*)d_in[3];
  const float* b_a    = (const float*)d_in[4];
  const float* Wq     = (const float*)d_in[5];
  const float* Wk     = (const float*)d_in[6];
  const float* Wv     = (const float*)d_in[7];
  const float* v_attn = (const float*)d_in[8];
  const float* Wih0   = (const float*)d_in[9];
  const float* Whh0   = (const float*)d_in[10];
  const float* b0     = (const float*)d_in[11];
  const float* Wih1   = (const float*)d_in[12];
  const float* Whh1   = (const float*)d_in[13];
  const float* b1     = (const float*)d_in[14];
  const float* Wd1    = (const float*)d_in[15];
  const float* bd1    = (const float*)d_in[16];
  const float* Wd2    = (const float*)d_in[17];
  const float* bd2    = (const float*)d_in[18];
  const float* Wc     = (const float*)d_in[19];
  const float* bc     = (const float*)d_in[20];
  const float* Wg     = (const float*)d_in[21];
  const float* bg     = (const float*)d_in[22];
  float* out = (float*)d_out;

  char* wsb = (char*)d_ws;
  ushortT*  u = (ushortT*)wsb;
  unsigned* R = (unsigned*)(wsb + RBYTE);

  conv_bf16<<<1024, 256, 0, stream>>>(Wq,    u + O_WQ,   (size_t)ATT*H);
  conv_bf16<<<1024, 256, 0, stream>>>(Wih_a, u + O_WIHA, (size_t)4*H*NMEL);
  conv_bf16<<<1024, 256, 0, stream>>>(Wih0,  u + O_WIH0, (size_t)4*H*DIN);
  conv_bf16<<<1024, 256, 0, stream>>>(Whh1,  u + O_WHH1, (size_t)4*H*H);
  conv_bf16<<<1024, 256, 0, stream>>>(Wd1,   u + O_WD1,  (size_t)H*H);
  conv_bf16<<<1024, 256, 0, stream>>>(Wd2,   u + O_WD2,  (size_t)H*H);
  prep_kv<<<TXT, 256, 0, stream>>>(text, Wk, Wv, u + O_KEYS, u + O_VALS);
  prep_zero<<<(RECN + 255)/256, 256, 0, stream>>>(R);

  ar_persist<<<GBK, NT, 0, stream>>>(residual, Whh_a, Whh0, Wih1,
      b_a, v_attn, b0, b1, bd1, bd2, Wc, bc, Wg, bg, out, d_ws);
}

// Round 12
// 11232.652 us; speedup vs baseline: 1.5141x; 1.5141x over previous
//
#include <hip/hip_runtime.h>
#include <hip/hip_bf16.h>
#include <math.h>

#define GBK 256          // grid blocks (1 per CU, co-resident)
#define NT  512          // threads per block (8 waves)

constexpr int T_STEPS = 600;
constexpr int TXT     = 200;
constexpr int NMEL    = 80;
constexpr int H       = 1024;
constexpr int ATT     = 640;
constexpr int DIN     = H + ATT;   // 1664
constexpr int GATE_B  = 200;       // gate-output block
constexpr int NPH     = 8;         // phases: 0:x 1:ha 2:q 3:sc 4:h0 5:h1 6:d1 7:d
constexpr int NREP    = 8;         // record replicas (poll-pressure spreading)

// ---- ws layout: bf16 region (ushort element offsets) ----
constexpr size_t O_WQ    = 0;                                  // 640*1024
constexpr size_t O_WIHA  = O_WQ   + (size_t)ATT*H;             // 4096*80
constexpr size_t O_WIH0  = O_WIHA + (size_t)4*H*NMEL;          // 4096*1664
constexpr size_t O_WHH1  = O_WIH0 + (size_t)4*H*DIN;           // 4096*1024
constexpr size_t O_WD1   = O_WHH1 + (size_t)4*H*H;             // 1024*1024
constexpr size_t O_WD2   = O_WD1  + (size_t)H*H;
constexpr size_t O_KEYS  = O_WD2  + (size_t)H*H;               // 200*640 row-major
constexpr size_t O_VALS  = O_KEYS + (size_t)TXT*ATT;           // 200*640 row-major
constexpr size_t O_END_U = O_VALS + (size_t)TXT*ATT;
constexpr size_t RBYTE   = ((O_END_U*2 + 255)/256)*256;        // record region
// records: NREP x NPH x 256 blocks x 32B; pair = [val|ep] 8B (RCCL-LL style)
constexpr int RECN = NREP*NPH*GBK*8;   // uints to zero

typedef unsigned short ushortT;
typedef ushortT us4 __attribute__((ext_vector_type(4)));
typedef ushortT us8 __attribute__((ext_vector_type(8)));
typedef unsigned uv2 __attribute__((ext_vector_type(2)));
typedef unsigned uv4 __attribute__((ext_vector_type(4)));

__device__ __forceinline__ float bf2f(ushortT u) {
  return __uint_as_float(((unsigned)u) << 16);
}
__device__ __forceinline__ ushortT f2bf(float x) {
  __hip_bfloat16 h = __float2bfloat16(x);
  ushortT u; __builtin_memcpy(&u, &h, 2); return u;
}
__device__ __forceinline__ us4 cvt4(float4 a) {
  return us4{ f2bf(a.x), f2bf(a.y), f2bf(a.z), f2bf(a.w) };
}
__device__ __forceinline__ float sigf(float x) { return 1.0f / (1.0f + expf(-x)); }
__device__ __forceinline__ float tanhfast(float x) {
  float e = __expf(2.0f * x);
  return (e - 1.0f) / (e + 1.0f);
}

__device__ __forceinline__ float red64(float v) {
  #pragma unroll
  for (int off = 32; off > 0; off >>= 1) v += __shfl_xor(v, off, 64);
  return v;
}

__device__ __forceinline__ unsigned* recptr(unsigned* R, int rep, int p, int b) {
  return R + ((size_t)((rep*NPH + p)*GBK + b) * 8);
}

// publish one 8B [val|ep] pair to all replicas (fire-and-forget)
__device__ __forceinline__ void rpub_pair(unsigned* R, int p, int b, int pairIdx,
                                          float v, unsigned e) {
  uv2 d; d.x = __float_as_uint(v); d.y = e;
  #pragma unroll
  for (int rep = 0; rep < NREP; ++rep) {
    unsigned* ptr = recptr(R, rep, p, b) + pairIdx*2;
    asm volatile("global_store_dwordx2 %0, %1, off sc0 sc1"
                 :: "v"(ptr), "v"(d) : "memory");
  }
}

// wait on a record, checking the first NCHK pair-epochs; returns up to 4 floats
template<int NCHK>
__device__ __forceinline__ float4 rwaitT(const unsigned* rec, unsigned e) {
  float4 o;
  if (NCHK == 1) {
    uv2 p;
    while (true) {
      asm volatile("global_load_dwordx2 %0, %1, off sc0 sc1\n\ts_waitcnt vmcnt(0)"
                   : "=v"(p) : "v"(rec) : "memory");
      if (p.y >= e) break;
      __builtin_amdgcn_s_sleep(1);
    }
    o.x = __uint_as_float(p.x); o.y = 0.f; o.z = 0.f; o.w = 0.f;
    return o;
  }
  uv4 lo, hi;
  const unsigned* r2 = rec + 4;
  while (true) {
    asm volatile("global_load_dwordx4 %0, %2, off sc0 sc1\n\t"
                 "global_load_dwordx4 %1, %3, off sc0 sc1\n\t"
                 "s_waitcnt vmcnt(0)"
                 : "=&v"(lo), "=&v"(hi) : "v"(rec), "v"(r2) : "memory");
    bool ok = (lo.y >= e) && (lo.w >= e);
    if (NCHK >= 3) ok = ok && (hi.y >= e);
    if (NCHK >= 4) ok = ok && (hi.w >= e);
    if (ok) break;
    __builtin_amdgcn_s_sleep(1);
  }
  o.x = __uint_as_float(lo.x); o.y = __uint_as_float(lo.z);
  o.z = __uint_as_float(hi.x); o.w = __uint_as_float(hi.z);
  return o;
}

// ---- conflict-free dots: lane handles float4/us4 index c*64+lane ----
__device__ __forceinline__ float dotbf(const ushortT* __restrict__ Wrow,
                                       const float* __restrict__ v, int lane) {
  const us4* w4 = (const us4*)Wrow;
  const float4* v4 = (const float4*)v;
  float s = 0.f;
  #pragma unroll
  for (int c = 0; c < 4; ++c) {
    us4 w = w4[c*64 + lane];
    float4 x = v4[c*64 + lane];
    s += bf2f(w[0])*x.x + bf2f(w[1])*x.y + bf2f(w[2])*x.z + bf2f(w[3])*x.w;
  }
  return s;
}
__device__ __forceinline__ float dotf(const float* __restrict__ Wrow,
                                      const float* __restrict__ v, int lane) {
  const float4* w4 = (const float4*)Wrow;
  const float4* v4 = (const float4*)v;
  float s = 0.f;
  #pragma unroll
  for (int c = 0; c < 4; ++c) {
    float4 w = w4[c*64 + lane], x = v4[c*64 + lane];
    s += w.x*x.x + w.y*x.y + w.z*x.z + w.w*x.w;
  }
  return s;
}
__device__ __forceinline__ float dot200(const float* __restrict__ a,
                                        const float* __restrict__ e, int lane) {
  float s = a[lane]*e[lane] + a[64+lane]*e[64+lane] + a[128+lane]*e[128+lane];
  if (lane < 8) s += a[192+lane]*e[192+lane];
  return s;
}

// ---------- prep kernels ----------
__global__ void conv_bf16(const float* __restrict__ src, ushortT* __restrict__ dst, size_t n) {
  size_t i  = blockIdx.x * (size_t)blockDim.x + threadIdx.x;
  size_t st = (size_t)gridDim.x * blockDim.x;
  for (; i < n; i += st) dst[i] = f2bf(src[i]);
}

__global__ void prep_kv(const float* __restrict__ text, const float* __restrict__ Wk,
                        const float* __restrict__ Wv, ushortT* __restrict__ keys,
                        ushortT* __restrict__ vals) {
  __shared__ float tx[ATT];
  const int t = blockIdx.x;
  for (int i = threadIdx.x; i < ATT; i += blockDim.x) tx[i] = text[(size_t)t*ATT + i];
  __syncthreads();
  for (int a = threadIdx.x; a < 2*ATT; a += blockDim.x) {
    const int which = (a >= ATT);
    const int ar = a - which*ATT;
    const float4* w4 = (const float4*)((which ? Wv : Wk) + (size_t)ar*ATT);
    const float4* t4 = (const float4*)tx;
    float s = 0.f;
    for (int i = 0; i < ATT/4; ++i) {
      float4 w = w4[i], x = t4[i];
      s += w.x*x.x + w.y*x.y + w.z*x.z + w.w*x.w;
    }
    (which ? vals : keys)[(size_t)t*ATT + ar] = f2bf(s);
  }
}

__global__ void prep_zero(unsigned* R) {
  int i = blockIdx.x * blockDim.x + threadIdx.x;
  if (i < RECN) R[i] = 0u;
}

// ---------- persistent AR kernel ----------
__global__ void __launch_bounds__(NT, 1)
ar_persist(const float* __restrict__ residual,
           const float* __restrict__ Whh_a, const float* __restrict__ Whh0g,
           const float* __restrict__ Wih1g,
           const float* __restrict__ b_a, const float* __restrict__ v_attn,
           const float* __restrict__ b0, const float* __restrict__ b1,
           const float* __restrict__ bd1, const float* __restrict__ bd2,
           const float* __restrict__ Wc, const float* __restrict__ bc,
           const float* __restrict__ Wg, const float* __restrict__ bg,
           float* __restrict__ out, void* __restrict__ wsraw)
{
  const int tid  = threadIdx.x;
  const int bid  = blockIdx.x;
  const int wid  = tid >> 6;     // 8 waves
  const int lane = tid & 63;
  const int rep  = bid & (NREP - 1);   // my poll replica

  const ushortT* uws = (const ushortT*)wsraw;
  unsigned* R = (unsigned*)((char*)wsraw + RBYTE);

  const ushortT* wq    = uws + O_WQ;
  const ushortT* wiha  = uws + O_WIHA;
  const ushortT* wih0s = uws + O_WIH0;
  const ushortT* whh1s = uws + O_WHH1;
  const ushortT* wd1   = uws + O_WD1;
  const ushortT* wd2   = uws + O_WD2;
  const ushortT* keys  = uws + O_KEYS;
  const ushortT* vals  = uws + O_VALS;

  // block owns units [bid*4, bid*4+4); 16 z-rows; wave wid -> rl 2w, 2w+1
  const int ub = bid*4;
  const int rlA = wid*2, rlB = wid*2 + 1;
  const int zrA = (rlA>>2)*H + ub + (rlA&3);
  const int zrB = (rlB>>2)*H + ub + (rlB&3);

  __shared__ __align__(16) ushortT lWhha[16*H];   // 32 KB
  __shared__ __align__(16) ushortT lWhh0[16*H];   // 32 KB
  __shared__ __align__(16) ushortT lWih1[16*H];   // 32 KB
  __shared__ __align__(16) ushortT lWd1[4*H];     // 8 KB
  __shared__ __align__(16) ushortT lWd2[4*H];     // 8 KB
  __shared__ __align__(16) ushortT lWq[3*H];      // 6 KB
  __shared__ __align__(16) float   V0[16*TXT];    // 12.8 KB
  __shared__ __align__(16) float   vg[TXT];
  __shared__ __align__(16) float   lvatt[ATT];
  __shared__ __align__(16) float   lha[H], lh0[H], lh1[H];
  __shared__ __align__(16) float   shq[ATT];
  __shared__ __align__(16) float   shv[H];
  __shared__ __align__(16) float   shx[128];
  __shared__ __align__(16) float   sce[TXT + 64];
  __shared__ float zl[16], zp[16], zaH[16], z0H[16], z1H[16];
  __shared__ float cA[4], c0S[4], c1S[4], misc2[4];

  // ---- init: stage LDS weights ----
  {
    us4* dA = (us4*)lWhha; us4* dC = (us4*)lWhh0; us4* dD = (us4*)lWih1;
    #pragma unroll
    for (int j = 0; j < 2; ++j) {
      const int rl = wid*2 + j;
      const int zr = (rl>>2)*H + ub + (rl&3);
      #pragma unroll
      for (int c = 0; c < 4; ++c) {
        const int ei = c*64 + lane;
        dA[rl*256 + ei] = cvt4(*(const float4*)(Whh_a + (size_t)zr*H + ei*4));
        dC[rl*256 + ei] = cvt4(*(const float4*)(Whh0g + (size_t)zr*H + ei*4));
        dD[rl*256 + ei] = cvt4(*(const float4*)(Wih1g + (size_t)zr*H + ei*4));
      }
    }
    if (wid < 4) {
      const us4* s1 = (const us4*)(wd1 + (size_t)(bid*4 + wid)*H);
      #pragma unroll
      for (int c = 0; c < 4; ++c)
        ((us4*)lWd1)[wid*256 + c*64 + lane] = s1[c*64 + lane];
    } else {
      const int w = wid - 4;
      const us4* s2 = (const us4*)(wd2 + (size_t)(bid*4 + w)*H);
      #pragma unroll
      for (int c = 0; c < 4; ++c)
        ((us4*)lWd2)[w*256 + c*64 + lane] = s2[c*64 + lane];
    }
    for (int w = 0; w < 3; ++w) {
      const int qr = bid + w*GBK;
      if (qr < ATT) {
        const us4* sq = (const us4*)(wq + (size_t)qr*H);
        for (int i = tid; i < 256; i += NT) ((us4*)lWq)[w*256 + i] = sq[i];
      }
    }
    for (int i = tid; i < ATT; i += NT) lvatt[i] = v_attn[i];
  }
  // ---- init: V0[r][t] = Wih0_row[H:] . v_t ; vg (gate block) ----
  for (int idx = tid; idx < 16*TXT; idx += NT) {
    const int r = idx / TXT, t = idx - r*TXT;
    const int zr = (r>>2)*H + ub + (r&3);
    const us8* wp = (const us8*)(wih0s + (size_t)zr*DIN + H);
    const us8* vp = (const us8*)(vals + (size_t)t*ATT);
    float acc = 0.f;
    for (int c = 0; c < ATT/8; ++c) {
      us8 w = wp[c], v = vp[c];
      #pragma unroll
      for (int e2 = 0; e2 < 8; ++e2) acc += bf2f(w[e2]) * bf2f(v[e2]);
    }
    V0[r*TXT + t] = acc;
  }
  if (bid == GATE_B) {
    for (int t = tid; t < TXT; t += NT) {
      const float4* wp = (const float4*)(Wg + H);
      const us4* vp = (const us4*)(vals + (size_t)t*ATT);
      float acc = 0.f;
      for (int c = 0; c < ATT/4; ++c) {
        float4 w = wp[c]; us4 v = vp[c];
        acc += w.x*bf2f(v[0]) + w.y*bf2f(v[1]) + w.z*bf2f(v[2]) + w.w*bf2f(v[3]);
      }
      vg[t] = acc;
    }
  }
  if (tid < 16) { zaH[tid] = 0.f; z0H[tid] = 0.f; z1H[tid] = 0.f; }
  if (tid < 4)  { cA[tid] = 0.f; c0S[tid] = 0.f; c1S[tid] = 0.f; }
  __syncthreads();

  for (int s = 0; s < T_STEPS; ++s) {
    const unsigned e = (unsigned)s + 1u;

    // ===== P1: consume x (phase0) ; ha ; publish pairs (tid 0-3 parallel) =====
    if (tid < NMEL) {
      float4 r = rwaitT<1>(recptr(R, rep, 0, tid), (unsigned)s);
      shx[tid] = r.x;
    }
    __syncthreads();
    {
      float sA = 0.f, sB = 0.f;
      if (lane < 20) {
        float4 xv = ((const float4*)shx)[lane];
        us4 w = ((const us4*)wiha)[(size_t)zrA*20 + lane];
        sA = bf2f(w[0])*xv.x + bf2f(w[1])*xv.y + bf2f(w[2])*xv.z + bf2f(w[3])*xv.w;
        w = ((const us4*)wiha)[(size_t)zrB*20 + lane];
        sB = bf2f(w[0])*xv.x + bf2f(w[1])*xv.y + bf2f(w[2])*xv.z + bf2f(w[3])*xv.w;
      }
      sA = red64(sA) + zaH[rlA] + b_a[zrA];
      sB = red64(sB) + zaH[rlB] + b_a[zrB];
      if (lane == 0) { zl[rlA] = sA; zl[rlB] = sB; }
    }
    __syncthreads();
    if (tid < 4) {
      float c = sigf(zl[4+tid])*cA[tid] + sigf(zl[tid])*tanhf(zl[8+tid]);
      cA[tid] = c;
      rpub_pair(R, 1, bid, tid, sigf(zl[12+tid])*tanhf(c), e);
    }

    // ===== P2: consume ha ; q (waves 0-2 parallel publish) ; zp ; SC score =====
    if (tid < GBK) {
      float4 r = rwaitT<4>(recptr(R, rep, 1, tid), e);
      ((float4*)lha)[tid] = r;
    }
    __syncthreads();
    if (wid < 3) {                         // q rows: wave w -> row bid + w*256
      if (wid < 2 || bid < ATT - 2*GBK) {
        float sq = red64(dotbf(lWq + wid*H, lha, lane));
        if (lane == 0) rpub_pair(R, 2, bid, wid, sq, e);
      }
    }
    if (bid == GATE_B && wid == 3) {
      float sg = red64(dotf(Wg, lha, lane));
      if (lane == 0) misc2[0] = sg;
    }
    {
      const bool earlyzp = (wid >= 4) || (bid >= TXT);
      if (earlyzp) {
        float sA = red64(dotbf(wih0s + (size_t)zrA*DIN, lha, lane)) + z0H[rlA] + b0[zrA];
        float sB = red64(dotbf(wih0s + (size_t)zrB*DIN, lha, lane)) + z0H[rlB] + b0[zrB];
        if (lane == 0) { zp[rlA] = sA; zp[rlB] = sB; }
      }
      if (bid < TXT) {
        if (tid < GBK) {                   // pairs 0,1 everywhere; pair 2 for tid<128
          float4 r = (tid < 128) ? rwaitT<3>(recptr(R, rep, 2, tid), e)
                                 : rwaitT<2>(recptr(R, rep, 2, tid), e);
          shq[tid] = r.x; shq[256 + tid] = r.y;
          if (tid < 128) shq[512 + tid] = r.z;
        }
        __syncthreads();
        if (wid == 0) {
          const us4* kp = (const us4*)(keys + (size_t)bid*ATT);
          float ss = 0.f;
          for (int c = lane; c < 160; c += 64) {
            us4 k = kp[c];
            float4 q4 = ((const float4*)shq)[c];
            float4 v4 = ((const float4*)lvatt)[c];
            ss += tanhfast(bf2f(k[0]) + q4.x)*v4.x + tanhfast(bf2f(k[1]) + q4.y)*v4.y
                + tanhfast(bf2f(k[2]) + q4.z)*v4.z + tanhfast(bf2f(k[3]) + q4.w)*v4.w;
          }
          ss = red64(ss);
          if (lane == 0) rpub_pair(R, 3, bid, 0, ss, e);
        }
      }
      if (!earlyzp) {
        float sA = red64(dotbf(wih0s + (size_t)zrA*DIN, lha, lane)) + z0H[rlA] + b0[zrA];
        float sB = red64(dotbf(wih0s + (size_t)zrB*DIN, lha, lane)) + z0H[rlB] + b0[zrB];
        if (lane == 0) { zp[rlA] = sA; zp[rlB] = sB; }
      }
    }

    // ===== P3: consume scores ; softmax ; h0 publish (tid 0-3) ; gate out =====
    if (tid < TXT) {
      float4 r = rwaitT<1>(recptr(R, rep, 3, tid), e);
      sce[tid] = __expf(r.x);              // |score| <= sum|v_attn| ~ 10: safe
    }
    __syncthreads();
    if (wid == 0) {
      float pz = sce[lane] + sce[64+lane] + sce[128+lane]
               + (lane < 8 ? sce[192+lane] : 0.f);
      pz = red64(pz);
      if (lane == 0) misc2[1] = 1.0f / pz;
    }
    {
      float rA = red64(dot200(V0 + rlA*TXT, sce, lane));
      float rB = red64(dot200(V0 + rlB*TXT, sce, lane));
      if (lane == 0) { zl[rlA] = rA; zl[rlB] = rB; }
    }
    __syncthreads();
    if (tid < 4) {
      const float invZ = misc2[1];
      float iv = zl[tid]*invZ    + zp[tid];
      float fv = zl[4+tid]*invZ  + zp[4+tid];
      float gv = zl[8+tid]*invZ  + zp[8+tid];
      float ov = zl[12+tid]*invZ + zp[12+tid];
      float c = sigf(fv)*c0S[tid] + sigf(iv)*tanhf(gv);
      c0S[tid] = c;
      rpub_pair(R, 4, bid, tid, sigf(ov)*tanhf(c), e);
    }
    if (bid == GATE_B && wid == 3) {
      float sg = red64(dot200(vg, sce, lane)) * misc2[1];
      if (lane == 0) out[T_STEPS*NMEL + s] = sigf(sg + misc2[0] + bg[0]);
    }

    // ===== P4: consume h0 ; z1 -> h1 publish (tid 0-3) ; shadow z0H =====
    if (tid < GBK) {
      float4 r = rwaitT<4>(recptr(R, rep, 4, tid), e);
      ((float4*)lh0)[tid] = r;
    }
    __syncthreads();
    {
      float sA = red64(dotbf(lWih1 + rlA*H, lh0, lane)) + z1H[rlA] + b1[zrA];
      float sB = red64(dotbf(lWih1 + rlB*H, lh0, lane)) + z1H[rlB] + b1[zrB];
      if (lane == 0) { zl[rlA] = sA; zl[rlB] = sB; }
    }
    __syncthreads();
    if (tid < 4) {
      float c = sigf(zl[4+tid])*c1S[tid] + sigf(zl[tid])*tanhf(zl[8+tid]);
      c1S[tid] = c;
      rpub_pair(R, 5, bid, tid, sigf(zl[12+tid])*tanhf(c), e);
    }
    {
      float pA = red64(dotbf(lWhh0 + rlA*H, lh0, lane));
      float pB = red64(dotbf(lWhh0 + rlB*H, lh0, lane));
      if (lane == 0) { z0H[rlA] = pA; z0H[rlB] = pB; }
    }

    // ===== P5: consume h1 ; d1 rows (waves 0-3 parallel publish) ; shadow zaH =====
    if (tid < GBK) {
      float4 r = rwaitT<4>(recptr(R, rep, 5, tid), e);
      ((float4*)lh1)[tid] = r;
    }
    __syncthreads();
    if (wid < 4) {
      const int r = bid*4 + wid;
      float t6 = red64(dotbf(lWd1 + wid*H, lh1, lane)) + bd1[r];
      if (lane == 0) rpub_pair(R, 6, bid, wid, tanhf(t6), e);
    }
    {
      float pA = red64(dotbf(lWhha + rlA*H, lha, lane));
      float pB = red64(dotbf(lWhha + rlB*H, lha, lane));
      if (lane == 0) { zaH[rlA] = pA; zaH[rlB] = pB; }
    }

    // ===== P6: consume d1 ; d rows (waves 0-3 parallel publish) ; shadow z1H =====
    if (tid < GBK) {
      float4 r = rwaitT<4>(recptr(R, rep, 6, tid), e);
      ((float4*)shv)[tid] = r;
    }
    __syncthreads();
    if (wid < 4) {
      const int r = bid*4 + wid;
      float t7 = red64(dotbf(lWd2 + wid*H, shv, lane)) + bd2[r];
      if (lane == 0) rpub_pair(R, 7, bid, wid, tanhf(t7), e);
    }
    {
      float pA = red64(dotbf(whh1s + (size_t)zrA*H, lh1, lane));
      float pB = red64(dotbf(whh1s + (size_t)zrB*H, lh1, lane));
      if (lane == 0) { z1H[rlA] = pA; z1H[rlB] = pB; }
    }

    // ===== P7 (blocks<80): consume d ; dec_out ; out ; publish x =====
    if (bid < NMEL) {
      __syncthreads();                 // protect shv (read by waves 0-3 in P6)
      if (tid < GBK) {
        float4 r = rwaitT<4>(recptr(R, rep, 7, tid), e);
        ((float4*)shv)[tid] = r;
      }
      __syncthreads();
      if (wid < 2) {
        const int r = wid*NMEL + bid;  // wid0: log_s, wid1: bb
        float s8 = red64(dotf(Wc + (size_t)r*H, shv, lane)) + bc[r];
        if (lane == 0) misc2[2 + wid] = s8;
      }
      __syncthreads();
      if (tid == 0) {
        const int idx = T_STEPS - 1 - s;
        const float r = residual[idx*NMEL + bid];
        const float o = (r - misc2[3]) * expf(-misc2[2]);
        out[idx*NMEL + bid] = o;
        rpub_pair(R, 0, bid, 0, o, e);
      }
    }
  }
}

extern "C" void kernel_launch(void* const* d_in, const int* in_sizes, int n_in,
                              void* d_out, int out_size, void* d_ws, size_t ws_size,
                              hipStream_t stream) {
  const float* residual = (const float*)d_in[0];
  const float* text   = (const float*)d_in[1];
  const float* Wih_a  = (const float*)d_in[2];
  const float* Whh_a  = (const float*)d_in[3];
  const float* b_a    = (const float*)d_in[4];
  const float* Wq     = (const float*)d_in[5];
  const float* Wk     = (const float*)d_in[6];
  const float* Wv     = (const float*)d_in[7];
  const float* v_attn = (const float*)d_in[8];
  const float* Wih0   = (const float*)d_in[9];
  const float* Whh0   = (const float*)d_in[10];
  const float* b0     = (const float*)d_in[11];
  const float* Wih1   = (const float*)d_in[12];
  const float* Whh1   = (const float*)d_in[13];
  const float* b1     = (const float*)d_in[14];
  const float* Wd1    = (const float*)d_in[15];
  const float* bd1    = (const float*)d_in[16];
  const float* Wd2    = (const float*)d_in[17];
  const float* bd2    = (const float*)d_in[18];
  const float* Wc     = (const float*)d_in[19];
  const float* bc     = (const float*)d_in[20];
  const float* Wg     = (const float*)d_in[21];
  const float* bg     = (const float*)d_in[22];
  float* out = (float*)d_out;

  char* wsb = (char*)d_ws;
  ushortT*  u = (ushortT*)wsb;
  unsigned* R = (unsigned*)(wsb + RBYTE);

  conv_bf16<<<1024, 256, 0, stream>>>(Wq,    u + O_WQ,   (size_t)ATT*H);
  conv_bf16<<<1024, 256, 0, stream>>>(Wih_a, u + O_WIHA, (size_t)4*H*NMEL);
  conv_bf16<<<1024, 256, 0, stream>>>(Wih0,  u + O_WIH0, (size_t)4*H*DIN);
  conv_bf16<<<1024, 256, 0, stream>>>(Whh1,  u + O_WHH1, (size_t)4*H*H);
  conv_bf16<<<1024, 256, 0, stream>>>(Wd1,   u + O_WD1,  (size_t)H*H);
  conv_bf16<<<1024, 256, 0, stream>>>(Wd2,   u + O_WD2,  (size_t)H*H);
  prep_kv<<<TXT, 256, 0, stream>>>(text, Wk, Wv, u + O_KEYS, u + O_VALS);
  prep_zero<<<(RECN + 255)/256, 256, 0, stream>>>(R);

  ar_persist<<<GBK, NT, 0, stream>>>(residual, Whh_a, Whh0, Wih1,
      b_a, v_attn, b0, b1, bd1, bd2, Wc, bc, Wg, bg, out, d_ws);
}